// Round 8
// baseline (174.077 us; speedup 1.0000x reference)
//
#include <hip/hip_runtime.h>
#include <hip/hip_bf16.h>

#define INF 128
#define OUTF 64
#define ALPHA 0.2f
#define EPSV 1e-6f

#define CHUNK_LOG 14
#define CHUNK (1 << CHUNK_LOG)      // 16384 edges per sort chunk

typedef __bf16 bf16x8 __attribute__((ext_vector_type(8)));
typedef float  f32x4  __attribute__((ext_vector_type(4)));
typedef float  f32x2  __attribute__((ext_vector_type(2)));

// D = S0*S1 + S2 packed over a VGPR pair (VOP3P). One inst = two v_fma_f32.
__device__ __forceinline__ void pkfma(f32x2& acc, f32x2 a, f32x2 b)
{
    asm("v_pk_fma_f32 %0, %1, %2, %0" : "+v"(acc) : "v"(a), "v"(b));
}
__device__ __forceinline__ f32x2 unp2(unsigned u)
{
    f32x2 r;
    r.x = __uint_as_float(u << 16);
    r.y = __uint_as_float(u & 0xffff0000u);
    return r;
}

// ---------------------------------------------------------------------------
// k_fc_sort (fat kernel, 512 threads): blk%9==8 -> counting-sort role, else
// FC role. NO GLOBAL ATOMICS (R3: 800K device atomics are issue-bound ~46us).
//
// Sort role: chunk of 16384 edges; full-keyspace histogram in LDS as packed
// u8 counters (4/u32). LDS atomicAdd return = within-chunk rank (rank8[e]).
// Histogram row dumped to H[chunk][Npad] (u8, read as u32 by colscan).
//
// FC role: 8 waves share one 32KB LDS weight staging (bf16 hi/lo split);
// each wave computes 16 rows. Whb interleaved [n][b][64] bf16; s1/s2 [n][b].
// ---------------------------------------------------------------------------
__global__ __launch_bounds__(512, 2)
void k_fc_sort(const float* __restrict__ h, const float* __restrict__ Wfc,
               const float* __restrict__ Wattn, __hip_bfloat16* __restrict__ Whb,
               float* __restrict__ s1, float* __restrict__ s2,
               const int* __restrict__ e_dst, unsigned char* __restrict__ rank8,
               unsigned char* __restrict__ H, int BN, int N, int Npad, int E,
               int nfc, int NB)
{
    __shared__ __align__(16) unsigned int s_mem[12512];   // 50048 B

    int blk = blockIdx.x;
    int g9 = blk / 9;
    int r9 = blk - 9 * g9;
    int tid = threadIdx.x;

    if (r9 == 8) {
        // ---- counting-sort role: chunk g9 ----
        if (g9 >= NB) return;
        int NW = Npad >> 2;                  // u32 words of counters
        for (int i = tid; i < NW; i += 512) s_mem[i] = 0u;
        __syncthreads();

        int ebase = g9 << CHUNK_LOG;
#pragma unroll
        for (int k = 0; k < CHUNK / 512; ++k) {
            int e = ebase + k * 512 + tid;
            if (e < E) {
                int d = e_dst[e];
                d = min(max(d, 0), N - 1);
                int w = d >> 2;
                int sh = (d & 3) << 3;
                unsigned old = atomicAdd(&s_mem[w], 1u << sh);
                rank8[e] = (unsigned char)((old >> sh) & 0xffu);
            }
        }
        __syncthreads();

        unsigned int* Hrow = (unsigned int*)(H + (size_t)g9 * Npad);
        for (int i = tid; i < NW; i += 512) Hrow[i] = s_mem[i];
        return;
    }

    // ---- FC role ----
    int fcid = g9 * 8 + r9;
    if (fcid >= nfc) return;

    bf16x8* s_whi = (bf16x8*)s_mem;            // 16 KB (1024 frags)
    bf16x8* s_wlo = (bf16x8*)(s_mem + 4096);   // 16 KB

    int lane = tid & 63;
    int wave = tid >> 6;
    int base = fcid * 128 + wave * 16;
    int q = lane & 15, quad = lane >> 4;

    // Prefetch this wave's h fragment (clamped row for OOB waves).
    int hr = min(base + q, BN - 1);
    const float* hrow = h + (size_t)hr * INF + quad * 8;
    float4 hp[8];
#pragma unroll
    for (int kb = 0; kb < 4; ++kb) {
        hp[2 * kb]     = *(const float4*)(hrow + kb * 32);
        hp[2 * kb + 1] = *(const float4*)(hrow + kb * 32 + 4);
    }

    // Cooperative weight load+split: thread owns row=tid>>3, 16 cols at
    // c*16 (c=tid&7) -> two 8-col fragments (quad indices 2c, 2c+1).
    {
        int row = tid >> 3;
        int c   = tid & 7;
        int kb  = c >> 1;
        int qu0 = (c & 1) * 2;
        int t   = row >> 4;
        int qq  = row & 15;
        const float* wp = Wfc + (size_t)row * INF + c * 16;
#pragma unroll
        for (int half = 0; half < 2; ++half) {
            float4 w0 = *(const float4*)(wp + half * 8);
            float4 w1 = *(const float4*)(wp + half * 8 + 4);
            float wv8[8] = {w0.x, w0.y, w0.z, w0.w, w1.x, w1.y, w1.z, w1.w};
            bf16x8 hi8, lo8;
#pragma unroll
            for (int j = 0; j < 8; ++j) {
                hi8[j] = (__bf16)wv8[j];
                lo8[j] = (__bf16)(wv8[j] - (float)hi8[j]);
            }
            int f = ((kb * 4 + t) * 4 + qu0 + half) * 16 + qq;
            s_whi[f] = hi8;
            s_wlo[f] = lo8;
        }
    }
    __syncthreads();

    if (base >= BN) return;   // OOB wave (no further barriers below)

    f32x4 acc[4];
#pragma unroll
    for (int t = 0; t < 4; ++t) acc[t] = (f32x4){0.f, 0.f, 0.f, 0.f};

#pragma unroll
    for (int kb = 0; kb < 4; ++kb) {
        float4 h0 = hp[2 * kb];
        float4 h1 = hp[2 * kb + 1];
        float hv8[8] = {h0.x, h0.y, h0.z, h0.w, h1.x, h1.y, h1.z, h1.w};
        bf16x8 ahi, alo;
#pragma unroll
        for (int j = 0; j < 8; ++j) {
            ahi[j] = (__bf16)hv8[j];
            alo[j] = (__bf16)(hv8[j] - (float)ahi[j]);
        }
#pragma unroll
        for (int t = 0; t < 4; ++t) {
            int f = ((kb * 4 + t) * 4 + quad) * 16 + q;
            bf16x8 wh = s_whi[f];
            bf16x8 wl = s_wlo[f];
            acc[t] = __builtin_amdgcn_mfma_f32_16x16x32_bf16(ahi, wh, acc[t], 0, 0, 0);
            acc[t] = __builtin_amdgcn_mfma_f32_16x16x32_bf16(ahi, wl, acc[t], 0, 0, 0);
            acc[t] = __builtin_amdgcn_mfma_f32_16x16x32_bf16(alo, wh, acc[t], 0, 0, 0);
        }
    }

#pragma unroll
    for (int rr4 = 0; rr4 < 4; ++rr4) {
        int rr = base + quad * 4 + rr4;
        int b = (rr >= N) ? 1 : 0;
        int n = rr - b * N;
        __hip_bfloat16* dst = Whb + (size_t)n * 128 + b * 64 + q;
#pragma unroll
        for (int t = 0; t < 4; ++t) dst[t * 16] = __float2bfloat16(acc[t][rr4]);
    }

    float aS[4], aD[4];
#pragma unroll
    for (int t = 0; t < 4; ++t) {
        aS[t] = Wattn[t * 16 + q];
        aD[t] = Wattn[OUTF + t * 16 + q];
    }
    float t1[4], t2[4];
#pragma unroll
    for (int rr4 = 0; rr4 < 4; ++rr4) {
        t1[rr4] = acc[0][rr4] * aS[0] + acc[1][rr4] * aS[1] + acc[2][rr4] * aS[2] + acc[3][rr4] * aS[3];
        t2[rr4] = acc[0][rr4] * aD[0] + acc[1][rr4] * aD[1] + acc[2][rr4] * aD[2] + acc[3][rr4] * aD[3];
    }
#pragma unroll
    for (int off = 1; off <= 8; off <<= 1) {
#pragma unroll
        for (int rr4 = 0; rr4 < 4; ++rr4) {
            t1[rr4] += __shfl_xor(t1[rr4], off, 64);
            t2[rr4] += __shfl_xor(t2[rr4], off, 64);
        }
    }
    if (q == 0) {
#pragma unroll
        for (int rr4 = 0; rr4 < 4; ++rr4) {
            int rr = base + quad * 4 + rr4;
            int b = (rr >= N) ? 1 : 0;
            int n = rr - b * N;
            s1[2 * n + b] = t1[rr4];
            s2[2 * n + b] = t2[rr4];
        }
    }
}

// ---------------------------------------------------------------------------
// k_colscan: thread per u32 word (4 packed-u8 buckets), exclusive scan along
// the chunk axis, 7-deep pre-issued load batches (MLP vs HBM latency).
// ---------------------------------------------------------------------------
__global__ __launch_bounds__(256)
void k_colscan(const unsigned int* __restrict__ H, unsigned int* __restrict__ P,
               int* __restrict__ deg, int N, int Npad, int NB)
{
    int w = blockIdx.x * 256 + threadIdx.x;
    int NW = Npad >> 2;
    if (w >= NW) return;

    unsigned r = 0;
    for (int b0 = 0; b0 < NB; b0 += 7) {
        unsigned hv[7];
#pragma unroll
        for (int j = 0; j < 7; ++j) {
            int b = b0 + j;
            hv[j] = (b < NB) ? H[(size_t)b * NW + w] : 0u;
        }
#pragma unroll
        for (int j = 0; j < 7; ++j) {
            int b = b0 + j;
            if (b < NB) {
                P[(size_t)b * NW + w] = r;
                r += hv[j];
            }
        }
    }

    int d0 = w * 4;
    if (d0 + 3 < N) {
        *(int4*)(deg + d0) = make_int4((int)(r & 0xffu), (int)((r >> 8) & 0xffu),
                                       (int)((r >> 16) & 0xffu), (int)((r >> 24) & 0xffu));
    } else {
        for (int j = 0; j < 4 && d0 + j < N; ++j) deg[d0 + j] = (int)((r >> (8 * j)) & 0xffu);
    }
}

// ---------------------------------------------------------------------------
// k_scan: each block redundantly computes its exclusive prefix from deg
// (L2-resident, 200KB), scans its 2048 elements, writes rowptr.
// ---------------------------------------------------------------------------
__global__ __launch_bounds__(256)
void k_scan(const int* __restrict__ deg, int* __restrict__ rowptr, int N, int E)
{
    int t = threadIdx.x, lane = t & 63, wave = t >> 6;
    __shared__ int pre_ws[4];
    __shared__ int wsum[4];

    int myStart = blockIdx.x * 2048;
    int s = 0;
    for (int i0 = t * 8; i0 < myStart; i0 += 2048) {
        int4 v0 = *(const int4*)(deg + i0);
        int4 v1 = *(const int4*)(deg + i0 + 4);
        s += v0.x + v0.y + v0.z + v0.w + v1.x + v1.y + v1.z + v1.w;
    }
#pragma unroll
    for (int off = 32; off >= 1; off >>= 1) s += __shfl_xor(s, off, 64);
    if (lane == 0) pre_ws[wave] = s;
    __syncthreads();
    int pre = pre_ws[0] + pre_ws[1] + pre_ws[2] + pre_ws[3];

    int base = myStart + t * 8;
    int vals[8]; int sl = 0;
#pragma unroll
    for (int j = 0; j < 8; ++j) {
        int i = base + j;
        vals[j] = (i < N) ? deg[i] : 0;
        sl += vals[j];
    }
    int inc = sl;
#pragma unroll
    for (int off = 1; off < 64; off <<= 1) {
        int u = __shfl_up(inc, off, 64);
        if (lane >= off) inc += u;
    }
    if (lane == 63) wsum[wave] = inc;
    __syncthreads();

    int woff = 0;
#pragma unroll
    for (int w = 0; w < 4; ++w) if (w < wave) woff += wsum[w];
    int running = pre + woff + (inc - sl);
#pragma unroll
    for (int j = 0; j < 8; ++j) {
        int i = base + j;
        if (i < N) rowptr[i] = running;
        running += vals[j];
    }
    if (blockIdx.x == 0 && t == 0) rowptr[N] = E;
}

// ---------------------------------------------------------------------------
// Scatter v8: SINGLE PASS (R6's 8x dst-partition read amplification reverted
// per its own pre-commitment: measured gain was <8us while costing ~51MB of
// replicated metadata reads -- R7 stacked exp on top of that and went
// neutral). 4 edges/thread, coalesced int4/u32 loads, x computed ONCE per
// edge here (gather stays the slim v7). Record: 8B (src, x0|x1<<16 bf16).
// ---------------------------------------------------------------------------
__global__ __launch_bounds__(256)
void k_scatter(const int* __restrict__ e_src, const int* __restrict__ e_dst,
               const float* __restrict__ s1, const float* __restrict__ s2,
               const int* __restrict__ rowptr, const unsigned char* __restrict__ rank8,
               const unsigned char* __restrict__ P, uint2* __restrict__ rec,
               int E, int N, int Npad)
{
    int base_e = (blockIdx.x * 256 + threadIdx.x) * 4;
    if (base_e >= E) return;

    if (base_e + 4 <= E) {
        const unsigned char* Prow = P + (size_t)(base_e >> CHUNK_LOG) * Npad;
        int4 s4 = *(const int4*)(e_src + base_e);
        int4 d4 = *(const int4*)(e_dst + base_e);
        unsigned rku = *(const unsigned*)(rank8 + base_e);
        int ss[4] = {s4.x, s4.y, s4.z, s4.w};
        int dd[4] = {d4.x, d4.y, d4.z, d4.w};
#pragma unroll
        for (int j = 0; j < 4; ++j) {
            int d = min(max(dd[j], 0), N - 1);
            int s = min(max(ss[j], 0), N - 1);
            int p = rowptr[d] + (int)Prow[d] + (int)((rku >> (8 * j)) & 0xffu);
            float2 vs = ((const float2*)s1)[s];
            float2 vd = ((const float2*)s2)[d];
            float e0 = vs.x + vd.x;
            float e1 = vs.y + vd.y;
            e0 = fmaxf(e0, ALPHA * e0);
            e1 = fmaxf(e1, ALPHA * e1);
            float x0 = __expf(e0);
            float x1 = __expf(e1);
            __hip_bfloat16 b0 = __float2bfloat16(x0);
            __hip_bfloat16 b1 = __float2bfloat16(x1);
            unsigned u0 = *(unsigned short*)&b0;
            unsigned u1 = *(unsigned short*)&b1;
            rec[p] = make_uint2((unsigned)s, u0 | (u1 << 16));
        }
    } else {
        for (int j = 0; j < 4 && base_e + j < E; ++j) {
            int e = base_e + j;
            int d = min(max(e_dst[e], 0), N - 1);
            int s = min(max(e_src[e], 0), N - 1);
            int p = rowptr[d] + (int)P[(size_t)(e >> CHUNK_LOG) * Npad + d] + (int)rank8[e];
            float2 vs = ((const float2*)s1)[s];
            float2 vd = ((const float2*)s2)[d];
            float e0 = vs.x + vd.x;
            float e1 = vs.y + vd.y;
            e0 = fmaxf(e0, ALPHA * e0);
            e1 = fmaxf(e1, ALPHA * e1);
            float x0 = __expf(e0);
            float x1 = __expf(e1);
            __hip_bfloat16 b0 = __float2bfloat16(x0);
            __hip_bfloat16 b1 = __float2bfloat16(x1);
            unsigned u0 = *(unsigned short*)&b0;
            unsigned u1 = *(unsigned short*)&b1;
            rec[p] = make_uint2((unsigned)s, u0 | (u1 << 16));
        }
    }
}

// ---------------------------------------------------------------------------
// k_gather v7 (unchanged): one wave per dst, 16 edges/iter, lane=(g,q).
// x pre-computed in scatter; v_pk_fma_f32 accumulate; all-lane epilogue.
// ---------------------------------------------------------------------------
__global__ __launch_bounds__(256)
void k_gather(const int* __restrict__ rowptr, const uint2* __restrict__ rec,
              const uint4* __restrict__ W, float* __restrict__ out, int N)
{
    int lane = threadIdx.x & 63;
    int d = blockIdx.x * 4 + (threadIdx.x >> 6);
    if (d >= N) return;
    int g = lane >> 4, q = lane & 15;
    int b = q >> 3;

    int beg = rowptr[d];
    int end = rowptr[d + 1];

    f32x2 a2[4];
#pragma unroll
    for (int j = 0; j < 4; ++j) a2[j] = (f32x2){0.f, 0.f};
    float nacc = 0.f;

    for (int i = beg; i < end; i += 16) {
        int e[4];
        uint2 r[4];
#pragma unroll
        for (int k = 0; k < 4; ++k) {
            e[k] = i + 4 * k + g;
            r[k] = rec[min(e[k], end - 1)];
        }
        uint4 w[4];
#pragma unroll
        for (int k = 0; k < 4; ++k) w[k] = W[(size_t)(int)r[k].x * 16 + q];
        float x[4];
#pragma unroll
        for (int k = 0; k < 4; ++k) {
            unsigned xu = b ? (r[k].y & 0xffff0000u) : (r[k].y << 16);
            x[k] = (e[k] < end) ? __uint_as_float(xu) : 0.f;
            nacc += x[k];
        }
#pragma unroll
        for (int k = 0; k < 4; ++k) {
            f32x2 xx; xx.x = x[k]; xx.y = x[k];
            pkfma(a2[0], xx, unp2(w[k].x));
            pkfma(a2[1], xx, unp2(w[k].y));
            pkfma(a2[2], xx, unp2(w[k].z));
            pkfma(a2[3], xx, unp2(w[k].w));
        }
    }

#pragma unroll
    for (int off = 16; off <= 32; off <<= 1) {
#pragma unroll
        for (int j = 0; j < 4; ++j) {
            a2[j].x += __shfl_xor(a2[j].x, off, 64);
            a2[j].y += __shfl_xor(a2[j].y, off, 64);
        }
        nacc += __shfl_xor(nacc, off, 64);
    }

    // all-lane epilogue: lane (g,q) owns features (q&7)*8 + 2g, +1 of batch b
    float inv = 1.f / (nacc + EPSV);
    f32x2 vv = (g == 0) ? a2[0] : (g == 1) ? a2[1] : (g == 2) ? a2[2] : a2[3];
    float v0 = vv.x * inv;
    float v1 = vv.y * inv;
    v0 = v0 > 0.f ? v0 : expm1f(v0);
    v1 = v1 > 0.f ? v1 : expm1f(v1);
    *(float2*)(out + ((size_t)b * N + d) * 64 + (q & 7) * 8 + 2 * g) = make_float2(v0, v1);
}

extern "C" void kernel_launch(void* const* d_in, const int* in_sizes, int n_in,
                              void* d_out, int out_size, void* d_ws, size_t ws_size,
                              hipStream_t stream)
{
    const float* h     = (const float*)d_in[0];
    const int*   ei    = (const int*)d_in[1];
    const float* Wfc   = (const float*)d_in[2];
    const float* Wattn = (const float*)d_in[3];
    float* out = (float*)d_out;

    int BN = in_sizes[0] / INF;     // B*N = 100000
    int N  = BN / 2;                // 50000
    int E  = in_sizes[1] / 2;       // 800000

    int Npad = (N + 15) & ~15;               // 50000 (u8 row stride, 16B-mult)
    int NB   = (E + CHUNK - 1) >> CHUNK_LOG; // 49 sort chunks

    // ws: Whb[BN*64] bf16 | rec[E] uint2 | s1[BN] | s2[BN] | deg[N] | rowptr[N+1]
    //   | rank8[E] u8 (16B-aligned) | H[NB*Npad] u8 | P[NB*Npad] u8
    __hip_bfloat16* Whb = (__hip_bfloat16*)d_ws;
    uint2*  rec    = (uint2*)(Whb + (size_t)BN * OUTF);
    float*  s1     = (float*)(rec + E);
    float*  s2     = s1 + BN;
    int*    deg    = (int*)(s2 + BN);
    int*    rowptr = deg + N;
    size_t rk_off = (((size_t)(rowptr + N + 1) - (size_t)d_ws) + 15) & ~(size_t)15;
    unsigned char* rank8 = (unsigned char*)d_ws + rk_off;
    unsigned char* Hbuf  = rank8 + (((size_t)E + 15) & ~(size_t)15);
    unsigned char* Pbuf  = Hbuf + (size_t)NB * Npad;

    int nfc = (BN + 127) / 128;              // 782 fc virtual blocks
    int ngroups = (nfc + 7) / 8;             // 98
    if (NB > ngroups) ngroups = NB;
    int grid = ngroups * 9;                  // 882

    int nscan = (N + 2047) / 2048;           // 25
    int NW = Npad >> 2;                      // 12500 u32 words

    k_fc_sort<<<grid, 512, 0, stream>>>(h, Wfc, Wattn, Whb, s1, s2,
                                        ei + E, rank8, Hbuf, BN, N, Npad, E, nfc, NB);
    k_colscan<<<(NW + 255) / 256, 256, 0, stream>>>((const unsigned int*)Hbuf,
                                                    (unsigned int*)Pbuf, deg, N, Npad, NB);
    k_scan<<<nscan, 256, 0, stream>>>(deg, rowptr, N, E);
    k_scatter<<<((E + 3) / 4 + 255) / 256, 256, 0, stream>>>(ei, ei + E, s1, s2,
                                                             rowptr, rank8, Pbuf, rec, E, N, Npad);
    k_gather<<<(N + 3) / 4, 256, 0, stream>>>(rowptr, rec, (const uint4*)Whb, out, N);
}

// Round 9
// 172.565 us; speedup vs baseline: 1.0088x; 1.0088x over previous
//
#include <hip/hip_runtime.h>
#include <hip/hip_bf16.h>

#define INF 128
#define OUTF 64
#define ALPHA 0.2f
#define EPSV 1e-6f

#define CHUNK_LOG 14
#define CHUNK (1 << CHUNK_LOG)      // 16384 edges per sort chunk

typedef __bf16 bf16x8 __attribute__((ext_vector_type(8)));
typedef float  f32x4  __attribute__((ext_vector_type(4)));
typedef float  f32x2  __attribute__((ext_vector_type(2)));

// D = S0*S1 + S2 packed over a VGPR pair (VOP3P). One inst = two v_fma_f32.
__device__ __forceinline__ void pkfma(f32x2& acc, f32x2 a, f32x2 b)
{
    asm("v_pk_fma_f32 %0, %1, %2, %0" : "+v"(acc) : "v"(a), "v"(b));
}
__device__ __forceinline__ f32x2 unp2(unsigned u)
{
    f32x2 r;
    r.x = __uint_as_float(u << 16);
    r.y = __uint_as_float(u & 0xffff0000u);
    return r;
}

// ---------------------------------------------------------------------------
// k_fc_sort (fat kernel, 512 threads): blk%9==8 -> counting-sort role, else
// FC role. NO GLOBAL ATOMICS (R3: 800K device atomics are issue-bound ~46us).
//
// Sort role: chunk of 16384 edges; full-keyspace histogram in LDS as packed
// u8 counters (4/u32). LDS atomicAdd return = within-chunk rank (rank8[e]).
// Histogram row dumped to H[chunk][Npad] (u8, read as u32 by colscan).
//
// FC role: 8 waves share one 32KB LDS weight staging (bf16 hi/lo split);
// each wave computes 16 rows. Whb interleaved [n][b][64] bf16; s1/s2 [n][b].
// ---------------------------------------------------------------------------
__global__ __launch_bounds__(512, 2)
void k_fc_sort(const float* __restrict__ h, const float* __restrict__ Wfc,
               const float* __restrict__ Wattn, __hip_bfloat16* __restrict__ Whb,
               float* __restrict__ s1, float* __restrict__ s2,
               const int* __restrict__ e_dst, unsigned char* __restrict__ rank8,
               unsigned char* __restrict__ H, int BN, int N, int Npad, int E,
               int nfc, int NB)
{
    __shared__ __align__(16) unsigned int s_mem[12512];   // 50048 B

    int blk = blockIdx.x;
    int g9 = blk / 9;
    int r9 = blk - 9 * g9;
    int tid = threadIdx.x;

    if (r9 == 8) {
        // ---- counting-sort role: chunk g9 ----
        if (g9 >= NB) return;
        int NW = Npad >> 2;                  // u32 words of counters
        for (int i = tid; i < NW; i += 512) s_mem[i] = 0u;
        __syncthreads();

        int ebase = g9 << CHUNK_LOG;
#pragma unroll
        for (int k = 0; k < CHUNK / 512; ++k) {
            int e = ebase + k * 512 + tid;
            if (e < E) {
                int d = e_dst[e];
                d = min(max(d, 0), N - 1);
                int w = d >> 2;
                int sh = (d & 3) << 3;
                unsigned old = atomicAdd(&s_mem[w], 1u << sh);
                rank8[e] = (unsigned char)((old >> sh) & 0xffu);
            }
        }
        __syncthreads();

        unsigned int* Hrow = (unsigned int*)(H + (size_t)g9 * Npad);
        for (int i = tid; i < NW; i += 512) Hrow[i] = s_mem[i];
        return;
    }

    // ---- FC role ----
    int fcid = g9 * 8 + r9;
    if (fcid >= nfc) return;

    bf16x8* s_whi = (bf16x8*)s_mem;            // 16 KB (1024 frags)
    bf16x8* s_wlo = (bf16x8*)(s_mem + 4096);   // 16 KB

    int lane = tid & 63;
    int wave = tid >> 6;
    int base = fcid * 128 + wave * 16;
    int q = lane & 15, quad = lane >> 4;

    // Prefetch this wave's h fragment (clamped row for OOB waves).
    int hr = min(base + q, BN - 1);
    const float* hrow = h + (size_t)hr * INF + quad * 8;
    float4 hp[8];
#pragma unroll
    for (int kb = 0; kb < 4; ++kb) {
        hp[2 * kb]     = *(const float4*)(hrow + kb * 32);
        hp[2 * kb + 1] = *(const float4*)(hrow + kb * 32 + 4);
    }

    // Cooperative weight load+split: thread owns row=tid>>3, 16 cols at
    // c*16 (c=tid&7) -> two 8-col fragments (quad indices 2c, 2c+1).
    {
        int row = tid >> 3;
        int c   = tid & 7;
        int kb  = c >> 1;
        int qu0 = (c & 1) * 2;
        int t   = row >> 4;
        int qq  = row & 15;
        const float* wp = Wfc + (size_t)row * INF + c * 16;
#pragma unroll
        for (int half = 0; half < 2; ++half) {
            float4 w0 = *(const float4*)(wp + half * 8);
            float4 w1 = *(const float4*)(wp + half * 8 + 4);
            float wv8[8] = {w0.x, w0.y, w0.z, w0.w, w1.x, w1.y, w1.z, w1.w};
            bf16x8 hi8, lo8;
#pragma unroll
            for (int j = 0; j < 8; ++j) {
                hi8[j] = (__bf16)wv8[j];
                lo8[j] = (__bf16)(wv8[j] - (float)hi8[j]);
            }
            int f = ((kb * 4 + t) * 4 + qu0 + half) * 16 + qq;
            s_whi[f] = hi8;
            s_wlo[f] = lo8;
        }
    }
    __syncthreads();

    if (base >= BN) return;   // OOB wave (no further barriers below)

    f32x4 acc[4];
#pragma unroll
    for (int t = 0; t < 4; ++t) acc[t] = (f32x4){0.f, 0.f, 0.f, 0.f};

#pragma unroll
    for (int kb = 0; kb < 4; ++kb) {
        float4 h0 = hp[2 * kb];
        float4 h1 = hp[2 * kb + 1];
        float hv8[8] = {h0.x, h0.y, h0.z, h0.w, h1.x, h1.y, h1.z, h1.w};
        bf16x8 ahi, alo;
#pragma unroll
        for (int j = 0; j < 8; ++j) {
            ahi[j] = (__bf16)hv8[j];
            alo[j] = (__bf16)(hv8[j] - (float)ahi[j]);
        }
#pragma unroll
        for (int t = 0; t < 4; ++t) {
            int f = ((kb * 4 + t) * 4 + quad) * 16 + q;
            bf16x8 wh = s_whi[f];
            bf16x8 wl = s_wlo[f];
            acc[t] = __builtin_amdgcn_mfma_f32_16x16x32_bf16(ahi, wh, acc[t], 0, 0, 0);
            acc[t] = __builtin_amdgcn_mfma_f32_16x16x32_bf16(ahi, wl, acc[t], 0, 0, 0);
            acc[t] = __builtin_amdgcn_mfma_f32_16x16x32_bf16(alo, wh, acc[t], 0, 0, 0);
        }
    }

#pragma unroll
    for (int rr4 = 0; rr4 < 4; ++rr4) {
        int rr = base + quad * 4 + rr4;
        int b = (rr >= N) ? 1 : 0;
        int n = rr - b * N;
        __hip_bfloat16* dst = Whb + (size_t)n * 128 + b * 64 + q;
#pragma unroll
        for (int t = 0; t < 4; ++t) dst[t * 16] = __float2bfloat16(acc[t][rr4]);
    }

    float aS[4], aD[4];
#pragma unroll
    for (int t = 0; t < 4; ++t) {
        aS[t] = Wattn[t * 16 + q];
        aD[t] = Wattn[OUTF + t * 16 + q];
    }
    float t1[4], t2[4];
#pragma unroll
    for (int rr4 = 0; rr4 < 4; ++rr4) {
        t1[rr4] = acc[0][rr4] * aS[0] + acc[1][rr4] * aS[1] + acc[2][rr4] * aS[2] + acc[3][rr4] * aS[3];
        t2[rr4] = acc[0][rr4] * aD[0] + acc[1][rr4] * aD[1] + acc[2][rr4] * aD[2] + acc[3][rr4] * aD[3];
    }
#pragma unroll
    for (int off = 1; off <= 8; off <<= 1) {
#pragma unroll
        for (int rr4 = 0; rr4 < 4; ++rr4) {
            t1[rr4] += __shfl_xor(t1[rr4], off, 64);
            t2[rr4] += __shfl_xor(t2[rr4], off, 64);
        }
    }
    if (q == 0) {
#pragma unroll
        for (int rr4 = 0; rr4 < 4; ++rr4) {
            int rr = base + quad * 4 + rr4;
            int b = (rr >= N) ? 1 : 0;
            int n = rr - b * N;
            s1[2 * n + b] = t1[rr4];
            s2[2 * n + b] = t2[rr4];
        }
    }
}

// ---------------------------------------------------------------------------
// k_colscan: thread per u32 word (4 packed-u8 buckets), exclusive scan along
// the chunk axis, 7-deep pre-issued load batches (MLP vs HBM latency).
// ---------------------------------------------------------------------------
__global__ __launch_bounds__(256)
void k_colscan(const unsigned int* __restrict__ H, unsigned int* __restrict__ P,
               int* __restrict__ deg, int N, int Npad, int NB)
{
    int w = blockIdx.x * 256 + threadIdx.x;
    int NW = Npad >> 2;
    if (w >= NW) return;

    unsigned r = 0;
    for (int b0 = 0; b0 < NB; b0 += 7) {
        unsigned hv[7];
#pragma unroll
        for (int j = 0; j < 7; ++j) {
            int b = b0 + j;
            hv[j] = (b < NB) ? H[(size_t)b * NW + w] : 0u;
        }
#pragma unroll
        for (int j = 0; j < 7; ++j) {
            int b = b0 + j;
            if (b < NB) {
                P[(size_t)b * NW + w] = r;
                r += hv[j];
            }
        }
    }

    int d0 = w * 4;
    if (d0 + 3 < N) {
        *(int4*)(deg + d0) = make_int4((int)(r & 0xffu), (int)((r >> 8) & 0xffu),
                                       (int)((r >> 16) & 0xffu), (int)((r >> 24) & 0xffu));
    } else {
        for (int j = 0; j < 4 && d0 + j < N; ++j) deg[d0 + j] = (int)((r >> (8 * j)) & 0xffu);
    }
}

// ---------------------------------------------------------------------------
// k_scan: each block redundantly computes its exclusive prefix from deg
// (L2-resident, 200KB), scans its 2048 elements, writes rowptr.
// ---------------------------------------------------------------------------
__global__ __launch_bounds__(256)
void k_scan(const int* __restrict__ deg, int* __restrict__ rowptr, int N, int E)
{
    int t = threadIdx.x, lane = t & 63, wave = t >> 6;
    __shared__ int pre_ws[4];
    __shared__ int wsum[4];

    int myStart = blockIdx.x * 2048;
    int s = 0;
    for (int i0 = t * 8; i0 < myStart; i0 += 2048) {
        int4 v0 = *(const int4*)(deg + i0);
        int4 v1 = *(const int4*)(deg + i0 + 4);
        s += v0.x + v0.y + v0.z + v0.w + v1.x + v1.y + v1.z + v1.w;
    }
#pragma unroll
    for (int off = 32; off >= 1; off >>= 1) s += __shfl_xor(s, off, 64);
    if (lane == 0) pre_ws[wave] = s;
    __syncthreads();
    int pre = pre_ws[0] + pre_ws[1] + pre_ws[2] + pre_ws[3];

    int base = myStart + t * 8;
    int vals[8]; int sl = 0;
#pragma unroll
    for (int j = 0; j < 8; ++j) {
        int i = base + j;
        vals[j] = (i < N) ? deg[i] : 0;
        sl += vals[j];
    }
    int inc = sl;
#pragma unroll
    for (int off = 1; off < 64; off <<= 1) {
        int u = __shfl_up(inc, off, 64);
        if (lane >= off) inc += u;
    }
    if (lane == 63) wsum[wave] = inc;
    __syncthreads();

    int woff = 0;
#pragma unroll
    for (int w = 0; w < 4; ++w) if (w < wave) woff += wsum[w];
    int running = pre + woff + (inc - sl);
#pragma unroll
    for (int j = 0; j < 8; ++j) {
        int i = base + j;
        if (i < N) rowptr[i] = running;
        running += vals[j];
    }
    if (blockIdx.x == 0 && t == 0) rowptr[N] = E;
}

// ---------------------------------------------------------------------------
// Scatter v9: single pass, 4 edges/thread, ALL hot loads/stores via u32 byte
// offsets from uniform SGPR bases (R8's (size_t) math forced 64-bit per-lane
// v_lshl_add_u64 chains -- the hidden VALU cost R6's PMC flagged at 80%
// VALUBusy). All buffers < 32MB so every offset fits u32.
// Record: 8B (src, x0|x1<<16 bf16).
// ---------------------------------------------------------------------------
__global__ __launch_bounds__(256)
void k_scatter(const int* __restrict__ e_src, const int* __restrict__ e_dst,
               const float* __restrict__ s1, const float* __restrict__ s2,
               const int* __restrict__ rowptr, const unsigned char* __restrict__ rank8,
               const unsigned char* __restrict__ P, uint2* __restrict__ rec,
               int E, int N, int Npad)
{
    int base_e = (blockIdx.x * 256 + threadIdx.x) * 4;
    if (base_e >= E) return;

    const char* s1B = (const char*)s1;
    const char* s2B = (const char*)s2;
    const char* rpB = (const char*)rowptr;
    char* recB = (char*)rec;
    // P-row offset for this thread's chunk (chunk<=48, Npad=50000 -> fits u32)
    unsigned pbase = (unsigned)(base_e >> CHUNK_LOG) * (unsigned)Npad;

    if (base_e + 4 <= E) {
        int4 s4 = *(const int4*)(e_src + base_e);
        int4 d4 = *(const int4*)(e_dst + base_e);
        unsigned rku = *(const unsigned*)(rank8 + base_e);
        int ss[4] = {s4.x, s4.y, s4.z, s4.w};
        int dd[4] = {d4.x, d4.y, d4.z, d4.w};
#pragma unroll
        for (int j = 0; j < 4; ++j) {
            unsigned d = (unsigned)min(max(dd[j], 0), N - 1);
            unsigned s = (unsigned)min(max(ss[j], 0), N - 1);
            int rp = *(const int*)(rpB + (d << 2));
            unsigned pr = P[pbase + d];
            int p = rp + (int)pr + (int)((rku >> (8 * j)) & 0xffu);
            float2 vs = *(const float2*)(s1B + (s << 3));
            float2 vd = *(const float2*)(s2B + (d << 3));
            float e0 = vs.x + vd.x;
            float e1 = vs.y + vd.y;
            e0 = fmaxf(e0, ALPHA * e0);
            e1 = fmaxf(e1, ALPHA * e1);
            float x0 = __expf(e0);
            float x1 = __expf(e1);
            __hip_bfloat16 b0 = __float2bfloat16(x0);
            __hip_bfloat16 b1 = __float2bfloat16(x1);
            unsigned u0 = *(unsigned short*)&b0;
            unsigned u1 = *(unsigned short*)&b1;
            *(uint2*)(recB + ((unsigned)p << 3)) = make_uint2(s, u0 | (u1 << 16));
        }
    } else {
        for (int j = 0; j < 4 && base_e + j < E; ++j) {
            int e = base_e + j;
            unsigned d = (unsigned)min(max(e_dst[e], 0), N - 1);
            unsigned s = (unsigned)min(max(e_src[e], 0), N - 1);
            int rp = *(const int*)(rpB + (d << 2));
            unsigned pr = P[(unsigned)(e >> CHUNK_LOG) * (unsigned)Npad + d];
            int p = rp + (int)pr + (int)rank8[e];
            float2 vs = *(const float2*)(s1B + (s << 3));
            float2 vd = *(const float2*)(s2B + (d << 3));
            float e0 = vs.x + vd.x;
            float e1 = vs.y + vd.y;
            e0 = fmaxf(e0, ALPHA * e0);
            e1 = fmaxf(e1, ALPHA * e1);
            float x0 = __expf(e0);
            float x1 = __expf(e1);
            __hip_bfloat16 b0 = __float2bfloat16(x0);
            __hip_bfloat16 b1 = __float2bfloat16(x1);
            unsigned u0 = *(unsigned short*)&b0;
            unsigned u1 = *(unsigned short*)&b1;
            *(uint2*)(recB + ((unsigned)p << 3)) = make_uint2(s, u0 | (u1 << 16));
        }
    }
}

// ---------------------------------------------------------------------------
// k_gather v9: one wave per dst, 16 edges/iter, lane=(g,q). u32 byte-offset
// addressing throughout (rec 6.4MB, Whb 25.6MB, out 25.6MB all < 4GB);
// __expf(v)-1 replaces libm expm1f (absolute error ~1e-7, below bf16 floor).
// x pre-computed in scatter; v_pk_fma_f32 accumulate; all-lane epilogue.
// ---------------------------------------------------------------------------
__global__ __launch_bounds__(256)
void k_gather(const int* __restrict__ rowptr, const uint2* __restrict__ rec,
              const uint4* __restrict__ W, float* __restrict__ out, int N)
{
    int lane = threadIdx.x & 63;
    int d = blockIdx.x * 4 + (threadIdx.x >> 6);
    if (d >= N) return;
    int g = lane >> 4, q = lane & 15;
    int b = q >> 3;

    const char* recB = (const char*)rec;
    const char* WB   = (const char*)W;
    const char* rpB  = (const char*)rowptr;

    int beg = *(const int*)(rpB + ((unsigned)d << 2));
    int end = *(const int*)(rpB + ((unsigned)d << 2) + 4);

    unsigned qo = (unsigned)q << 4;       // q*16 bytes within a 256B W row

    f32x2 a2[4];
#pragma unroll
    for (int j = 0; j < 4; ++j) a2[j] = (f32x2){0.f, 0.f};
    float nacc = 0.f;

    for (int i = beg; i < end; i += 16) {
        int e[4];
        uint2 r[4];
#pragma unroll
        for (int k = 0; k < 4; ++k) {
            e[k] = i + 4 * k + g;
            unsigned eo = (unsigned)min(e[k], end - 1) << 3;
            r[k] = *(const uint2*)(recB + eo);
        }
        uint4 w[4];
#pragma unroll
        for (int k = 0; k < 4; ++k) {
            unsigned wo = (r[k].x << 8) + qo;   // src*256 + q*16
            w[k] = *(const uint4*)(WB + wo);
        }
        float x[4];
#pragma unroll
        for (int k = 0; k < 4; ++k) {
            unsigned xu = b ? (r[k].y & 0xffff0000u) : (r[k].y << 16);
            x[k] = (e[k] < end) ? __uint_as_float(xu) : 0.f;
            nacc += x[k];
        }
#pragma unroll
        for (int k = 0; k < 4; ++k) {
            f32x2 xx; xx.x = x[k]; xx.y = x[k];
            pkfma(a2[0], xx, unp2(w[k].x));
            pkfma(a2[1], xx, unp2(w[k].y));
            pkfma(a2[2], xx, unp2(w[k].z));
            pkfma(a2[3], xx, unp2(w[k].w));
        }
    }

#pragma unroll
    for (int off = 16; off <= 32; off <<= 1) {
#pragma unroll
        for (int j = 0; j < 4; ++j) {
            a2[j].x += __shfl_xor(a2[j].x, off, 64);
            a2[j].y += __shfl_xor(a2[j].y, off, 64);
        }
        nacc += __shfl_xor(nacc, off, 64);
    }

    // all-lane epilogue: lane (g,q) owns features (q&7)*8 + 2g, +1 of batch b
    float inv = 1.f / (nacc + EPSV);
    f32x2 vv = (g == 0) ? a2[0] : (g == 1) ? a2[1] : (g == 2) ? a2[2] : a2[3];
    float v0 = vv.x * inv;
    float v1 = vv.y * inv;
    v0 = v0 > 0.f ? v0 : (__expf(v0) - 1.f);
    v1 = v1 > 0.f ? v1 : (__expf(v1) - 1.f);
    unsigned oo = (((unsigned)b * (unsigned)N + (unsigned)d) * 64u
                   + (unsigned)((q & 7) * 8 + 2 * g)) << 2;
    *(float2*)((char*)out + oo) = make_float2(v0, v1);
}

extern "C" void kernel_launch(void* const* d_in, const int* in_sizes, int n_in,
                              void* d_out, int out_size, void* d_ws, size_t ws_size,
                              hipStream_t stream)
{
    const float* h     = (const float*)d_in[0];
    const int*   ei    = (const int*)d_in[1];
    const float* Wfc   = (const float*)d_in[2];
    const float* Wattn = (const float*)d_in[3];
    float* out = (float*)d_out;

    int BN = in_sizes[0] / INF;     // B*N = 100000
    int N  = BN / 2;                // 50000
    int E  = in_sizes[1] / 2;       // 800000

    int Npad = (N + 15) & ~15;               // 50000 (u8 row stride, 16B-mult)
    int NB   = (E + CHUNK - 1) >> CHUNK_LOG; // 49 sort chunks

    // ws: Whb[BN*64] bf16 | rec[E] uint2 | s1[BN] | s2[BN] | deg[N] | rowptr[N+1]
    //   | rank8[E] u8 (16B-aligned) | H[NB*Npad] u8 | P[NB*Npad] u8
    __hip_bfloat16* Whb = (__hip_bfloat16*)d_ws;
    uint2*  rec    = (uint2*)(Whb + (size_t)BN * OUTF);
    float*  s1     = (float*)(rec + E);
    float*  s2     = s1 + BN;
    int*    deg    = (int*)(s2 + BN);
    int*    rowptr = deg + N;
    size_t rk_off = (((size_t)(rowptr + N + 1) - (size_t)d_ws) + 15) & ~(size_t)15;
    unsigned char* rank8 = (unsigned char*)d_ws + rk_off;
    unsigned char* Hbuf  = rank8 + (((size_t)E + 15) & ~(size_t)15);
    unsigned char* Pbuf  = Hbuf + (size_t)NB * Npad;

    int nfc = (BN + 127) / 128;              // 782 fc virtual blocks
    int ngroups = (nfc + 7) / 8;             // 98
    if (NB > ngroups) ngroups = NB;
    int grid = ngroups * 9;                  // 882

    int nscan = (N + 2047) / 2048;           // 25
    int NW = Npad >> 2;                      // 12500 u32 words

    k_fc_sort<<<grid, 512, 0, stream>>>(h, Wfc, Wattn, Whb, s1, s2,
                                        ei + E, rank8, Hbuf, BN, N, Npad, E, nfc, NB);
    k_colscan<<<(NW + 255) / 256, 256, 0, stream>>>((const unsigned int*)Hbuf,
                                                    (unsigned int*)Pbuf, deg, N, Npad, NB);
    k_scan<<<nscan, 256, 0, stream>>>(deg, rowptr, N, E);
    k_scatter<<<((E + 3) / 4 + 255) / 256, 256, 0, stream>>>(ei, ei + E, s1, s2,
                                                             rowptr, rank8, Pbuf, rec, E, N, Npad);
    k_gather<<<(N + 3) / 4, 256, 0, stream>>>(rowptr, rec, (const uint4*)Whb, out, N);
}